// Round 8
// baseline (157.698 us; speedup 1.0000x reference)
//
#include <hip/hip_runtime.h>
#include <hip/hip_bf16.h>

#define DEV static __device__ __forceinline__

typedef __attribute__((ext_vector_type(8))) short short8;
typedef __attribute__((ext_vector_type(4))) short short4v;
typedef __attribute__((ext_vector_type(4))) float float4v;
typedef __attribute__((ext_vector_type(4))) int int4v;

DEV unsigned short f2bf(float f) {
  unsigned int u = __builtin_bit_cast(unsigned int, f);
  u = (u + 0x7fffu + ((u >> 16) & 1u)) >> 16;
  return (unsigned short)u;
}

DEV __attribute__((address_space(3))) void* to_lds(void* p) {
  return (__attribute__((address_space(3))) void*)p;
}
DEV const __attribute__((address_space(1))) void* to_glb(const void* p) {
  return (const __attribute__((address_space(1))) void*)p;
}

DEV float4v zero4() { float4v z = {0.f, 0.f, 0.f, 0.f}; return z; }

DEV float ex2(float x) {
  float r;
  asm("v_exp_f32 %0, %1" : "=v"(r) : "v"(x));
  return r;
}
DEV unsigned int cvtpk(float lo, float hi) {
  unsigned int r;
  asm("v_cvt_pk_bf16_f32 %0, %1, %2" : "=v"(r) : "v"(lo), "v"(hi));
  return r;
}

// ---------------------------------------------------------------- convert
__global__ __launch_bounds__(256)
void f32_to_bf16_kn(const float* __restrict__ src, unsigned short* __restrict__ dst, int n) {
  int i = (blockIdx.x * blockDim.x + threadIdx.x) * 4;
  int stride = gridDim.x * blockDim.x * 4;
  for (; i < n; i += stride) {
    float4v v = *reinterpret_cast<const float4v*>(src + i);
    short4v o;
    o[0] = (short)f2bf(v[0]);
    o[1] = (short)f2bf(v[1]);
    o[2] = (short)f2bf(v[2]);
    o[3] = (short)f2bf(v[3]);
    *reinterpret_cast<short4v*>(dst + i) = o;
  }
}

// ---------------------------------------------------------------- big-tile GEMM body
// C[m,n] = sum_k A[m,k]*B[n,k] + bias[n]. BM=256, BK=64, 8 waves (512 thr),
// double-buffered LDS, counted-vmcnt pipeline with RAW s_barrier (no
// __syncthreads -> no vmcnt(0) drain; staging stays in flight across steps).
// EPI==1: f32 out + bias (ldc=N). EPI==2: qkv split epilogue (q scaled by
// 0.125*log2e, k plain, v transposed to vt[(b*16+h)*64+d][t]).
// NOTE: device-inline template body wrapped by concrete __global__ kernels
// (templated __global__ + <<<>>> fails to emit device stubs in this toolchain).
template<int BN, int WM, int WN, int EPI>
DEV void gemm256_body(const unsigned short* __restrict__ A, const unsigned short* __restrict__ B,
                      const float* __restrict__ bias, void* __restrict__ Cout,
                      unsigned short* __restrict__ vtout, int M, int N, int K,
                      unsigned short* sAraw, unsigned short* sBraw) {
  constexpr int MF = 256 / (WM * 16);  // A frags per wave
  constexpr int NF = BN / (WN * 16);   // B frags per wave
  constexpr int BPASS = BN / 64;       // B staging passes (A is 4)
  const int t = threadIdx.x;
  const int lane = t & 63;
  const int wid = t >> 6;
  const int l15 = lane & 15, l4 = lane >> 4;
  const int wm = wid / WN, wn = wid % WN;
  const int wrow = wm * MF * 16, wcol = wn * NF * 16;
  const int gx = gridDim.x;
  const int nwg = gx * gridDim.y;
  const int lid = blockIdx.y * gx + blockIdx.x;
  const int swz = (lid & 7) * (nwg >> 3) + (lid >> 3);  // nwg % 8 == 0
  const int m0 = (swz / gx) * 256, n0 = (swz % gx) * BN;
  const int lkey = (l15 & 7) << 4;

  float4v acc[MF][NF];
#pragma unroll
  for (int i = 0; i < MF; i++)
#pragma unroll
    for (int j = 0; j < NF; j++) acc[i][j] = zero4();

  auto stage = [&](int bi, int k0) {
#pragma unroll
    for (int i = 0; i < 4; i++) {
      int unit = t + i * 512;
      int row = unit >> 3, sl = unit & 7;
      const unsigned short* g = &A[(size_t)(m0 + row) * K + k0 + (sl ^ (row & 7)) * 8];
      __builtin_amdgcn_global_load_lds(to_glb(g), to_lds(&sAraw[bi * 256 * 64 + unit * 8]), 16, 0, 0);
    }
#pragma unroll
    for (int i = 0; i < BPASS; i++) {
      int unit = t + i * 512;
      int row = unit >> 3, sl = unit & 7;
      const unsigned short* g = &B[(size_t)(n0 + row) * K + k0 + (sl ^ (row & 7)) * 8];
      __builtin_amdgcn_global_load_lds(to_glb(g), to_lds(&sBraw[bi * BN * 64 + unit * 8]), 16, 0, 0);
    }
  };

  stage(0, 0);
  const int nk = K >> 6;
  for (int s = 0; s < nk; ++s) {
    const int cur = s & 1;
    if (s + 1 < nk) {
      stage(cur ^ 1, (s + 1) << 6);
      // wait only for stage(s): leave the 4+BPASS just-issued loads in flight
      if constexpr (BPASS == 3)
        asm volatile("s_waitcnt vmcnt(7)");
      else
        asm volatile("s_waitcnt vmcnt(6)");
    } else {
      asm volatile("s_waitcnt vmcnt(0)");
    }
    __builtin_amdgcn_sched_barrier(0);
    __builtin_amdgcn_s_barrier();  // everyone's stage(s) landed
    __builtin_amdgcn_sched_barrier(0);

    const char* Ab = (const char*)&sAraw[cur * 256 * 64];
    const char* Bb = (const char*)&sBraw[cur * BN * 64];
    short8 bfr[NF][2];
#pragma unroll
    for (int nf = 0; nf < NF; nf++)
#pragma unroll
      for (int kc = 0; kc < 2; kc++) {
        int off = ((wcol + nf * 16 + l15) * 128 + kc * 64 + l4 * 16) ^ lkey;
        bfr[nf][kc] = *reinterpret_cast<const short8*>(Bb + off);
      }
#pragma unroll
    for (int g = 0; g < MF; g += 4) {
      short8 afr[4][2];
#pragma unroll
      for (int i = 0; i < 4; i++)
#pragma unroll
        for (int kc = 0; kc < 2; kc++) {
          int off = ((wrow + (g + i) * 16 + l15) * 128 + kc * 64 + l4 * 16) ^ lkey;
          afr[i][kc] = *reinterpret_cast<const short8*>(Ab + off);
        }
      __builtin_amdgcn_s_setprio(1);
#pragma unroll
      for (int kc = 0; kc < 2; kc++)
#pragma unroll
        for (int i = 0; i < 4; i++)
#pragma unroll
          for (int nf = 0; nf < NF; nf++)
            acc[g + i][nf] =
                __builtin_amdgcn_mfma_f32_16x16x32_bf16(afr[i][kc], bfr[nf][kc], acc[g + i][nf], 0, 0, 0);
      __builtin_amdgcn_s_setprio(0);
    }
    asm volatile("s_waitcnt lgkmcnt(0)" ::: "memory");  // my reads of buf[cur] done
    __builtin_amdgcn_sched_barrier(0);
    __builtin_amdgcn_s_barrier();  // all reads done -> buf[cur] may be overwritten
    __builtin_amdgcn_sched_barrier(0);
  }

#pragma unroll
  for (int mf = 0; mf < MF; mf++) {
    const int row0 = m0 + wrow + mf * 16 + l4 * 4;
#pragma unroll
    for (int nf = 0; nf < NF; nf++) {
      const int col = n0 + wcol + nf * 16 + l15;
      float vv[4];
#pragma unroll
      for (int r = 0; r < 4; r++) vv[r] = acc[mf][nf][r] + bias[col];
      if (EPI == 1) {
#pragma unroll
        for (int r = 0; r < 4; r++)
          ((float*)Cout)[(size_t)(row0 + r) * N + col] = vv[r];
      } else {
        if (col < 2048) {
          const float sc = (col < 1024) ? 0.18033688f : 1.0f;  // 0.125*log2(e) on q
#pragma unroll
          for (int r = 0; r < 4; r++)
            ((unsigned short*)Cout)[(size_t)(row0 + r) * 2048 + col] = f2bf(vv[r] * sc);
        } else {
          const int hv = col - 2048;
          const int R = ((row0 >> 11) * 16 + (hv >> 6)) * 64 + (hv & 63);
          const int tc = row0 & 2047;
          unsigned long long w = (unsigned long long)cvtpk(vv[0], vv[1]) |
                                 ((unsigned long long)cvtpk(vv[2], vv[3]) << 32);
          *(unsigned long long*)&vtout[(size_t)R * 2048 + tc] = w;
        }
      }
    }
  }
}

// QKV: BN=192, waves 2x4, split epilogue
__global__ __launch_bounds__(512, 2)
void gemm256_qkv_kn(const unsigned short* __restrict__ A, const unsigned short* __restrict__ B,
                    const float* __restrict__ bias, unsigned short* __restrict__ qkout,
                    unsigned short* __restrict__ vtout, int M, int N, int K) {
  __shared__ unsigned short sA[2][256 * 64];
  __shared__ unsigned short sB[2][192 * 64];
  gemm256_body<192, 2, 4, 2>(A, B, bias, qkout, vtout, M, N, K, &sA[0][0], &sB[0][0]);
}

// proj: BN=128, waves 4x2, f32 out
__global__ __launch_bounds__(512, 2)
void gemm256_proj_kn(const unsigned short* __restrict__ A, const unsigned short* __restrict__ B,
                     const float* __restrict__ bias, float* __restrict__ Cout,
                     int M, int N, int K) {
  __shared__ unsigned short sA[2][256 * 64];
  __shared__ unsigned short sB[2][128 * 64];
  gemm256_body<128, 4, 2, 1>(A, B, bias, Cout, nullptr, M, N, K, &sA[0][0], &sB[0][0]);
}

// ---------------------------------------------------------------- attention
// (unchanged from R6) 128-q blocks (4 waves x 32 q), static softmax in log2
// units, K and V^T staged via linear global_load_lds, l via ones-MFMA.
__global__ __launch_bounds__(256, 3)
void attn_kn(const unsigned short* __restrict__ qk, const unsigned short* __restrict__ vt,
             unsigned short* __restrict__ y) {
  __shared__ unsigned short sK[2][4096];  // [64 kv][64 d], key (kv&7)<<4
  __shared__ unsigned short sV[2][4096];  // [64 d][64 kv], key (d&7)<<4
  __shared__ unsigned short sP[4][2048];  // per-wave [32 q][64 kv], key (q&7)<<4
  const int t = threadIdx.x;
  const int wave = t >> 6, lane = t & 63;
  const int l15 = lane & 15, l4 = lane >> 4;
  const int bh = blockIdx.x, b = bh >> 4, h = bh & 15;
  const int yb_ = blockIdx.y;
  const int qt = ((yb_ >> 2) & 1) ? ((yb_ < 8) ? yb_ + 4 : yb_ - 12) : 15 - yb_;
  const int q0w = qt * 128 + wave * 32;
  const size_t base = (size_t)b * 2048 * 2048;
  const unsigned short* Qp = qk + base + h * 64;
  const unsigned short* Kp = Qp + 1024;
  const unsigned short* Vt = vt + (size_t)bh * 64 * 2048;
  unsigned short* yb = y + (size_t)b * 2048 * 1024 + h * 64;

  short8 ones8;
#pragma unroll
  for (int j = 0; j < 8; j++) ones8[j] = (short)0x3F80;

  short8 qf[2][2];
#pragma unroll
  for (int m = 0; m < 2; m++)
#pragma unroll
    for (int kc = 0; kc < 2; kc++)
      qf[m][kc] = *reinterpret_cast<const short8*>(
          &Qp[(size_t)(q0w + m * 16 + l15) * 2048 + kc * 32 + l4 * 8]);

  float4v o_acc[2][4];
#pragma unroll
  for (int m = 0; m < 2; m++)
#pragma unroll
    for (int f = 0; f < 4; f++) o_acc[m][f] = zero4();
  float4v acc_l[2] = {zero4(), zero4()};

  auto stage_k = [&](int kv0, int bi) {
#pragma unroll
    for (int i = 0; i < 2; i++) {
      int unit = t + i * 256;
      int row = unit >> 3, sl = unit & 7;
      const unsigned short* g = Kp + (size_t)(kv0 + row) * 2048 + (sl ^ (row & 7)) * 8;
      __builtin_amdgcn_global_load_lds(to_glb(g), to_lds(&sK[bi][unit * 8]), 16, 0, 0);
    }
  };
  auto stage_v = [&](int kv0, int bi) {
#pragma unroll
    for (int i = 0; i < 2; i++) {
      int unit = t + i * 256;
      int d = unit >> 3, sl = unit & 7;
      const unsigned short* g = Vt + (size_t)d * 2048 + kv0 + (sl ^ (d & 7)) * 8;
      __builtin_amdgcn_global_load_lds(to_glb(g), to_lds(&sV[bi][unit * 8]), 16, 0, 0);
    }
  };

  const int nt = 2 * qt + 2;
  stage_k(0, 0);
  stage_v(0, 0);
  __syncthreads();

  for (int ti = 0; ti < nt; ti++) {
    const int cur = ti & 1;
    const int kv0 = ti * 64;
    const bool last = (ti + 1 == nt);
    if (!last) { stage_k(kv0 + 64, cur ^ 1); stage_v(kv0 + 64, cur ^ 1); }

    if (kv0 <= q0w + 31) {
      const char* Kb = (const char*)sK[cur];
      const char* Vb = (const char*)sV[cur];
      char* Pb = (char*)sP[wave];

      float4v st[2][4];
#pragma unroll
      for (int m = 0; m < 2; m++)
#pragma unroll
        for (int c = 0; c < 4; c++) st[m][c] = zero4();
#pragma unroll
      for (int kc = 0; kc < 2; kc++) {
        short8 ka[4];
#pragma unroll
        for (int c = 0; c < 4; c++) {
          int off = ((c * 16 + l15) * 128 + kc * 64 + l4 * 16) ^ ((l15 & 7) << 4);
          ka[c] = *reinterpret_cast<const short8*>(Kb + off);
        }
        __builtin_amdgcn_s_setprio(1);
#pragma unroll
        for (int c = 0; c < 4; c++) {
          st[0][c] = __builtin_amdgcn_mfma_f32_16x16x32_bf16(ka[c], qf[0][kc], st[0][c], 0, 0, 0);
          st[1][c] = __builtin_amdgcn_mfma_f32_16x16x32_bf16(ka[c], qf[1][kc], st[1][c], 0, 0, 0);
        }
        __builtin_amdgcn_s_setprio(0);
      }

#pragma unroll
      for (int m = 0; m < 2; m++) {
        if (kv0 + 63 > q0w + m * 16) {
          const int qrow = q0w + m * 16 + l15;
#pragma unroll
          for (int c = 0; c < 4; c++)
#pragma unroll
            for (int r = 0; r < 4; r++) {
              int kv = kv0 + c * 16 + l4 * 4 + r;
              if (kv > qrow) st[m][c][r] = -1e30f;
            }
        }
#pragma unroll
        for (int c = 0; c < 4; c++) {
          float p0 = ex2(st[m][c][0]), p1 = ex2(st[m][c][1]);
          float p2 = ex2(st[m][c][2]), p3 = ex2(st[m][c][3]);
          unsigned long long w = (unsigned long long)cvtpk(p0, p1) |
                                 ((unsigned long long)cvtpk(p2, p3) << 32);
          int off = ((m * 16 + l15) * 128 + (c * 16 + l4 * 4) * 2) ^ ((l15 & 7) << 4);
          *(unsigned long long*)(Pb + off) = w;
        }
      }
      asm volatile("s_waitcnt lgkmcnt(0)" ::: "memory");
      __builtin_amdgcn_sched_barrier(0);

#pragma unroll
      for (int kc = 0; kc < 2; kc++) {
        short8 pa[2];
#pragma unroll
        for (int m = 0; m < 2; m++) {
          int off = ((m * 16 + l15) * 128 + kc * 64 + l4 * 16) ^ ((l15 & 7) << 4);
          pa[m] = *reinterpret_cast<const short8*>(Pb + off);
        }
        short8 vbf[4];
#pragma unroll
        for (int f = 0; f < 4; f++) {
          int d = f * 16 + l15;
          int off = (d * 128 + kc * 64 + l4 * 16) ^ ((d & 7) << 4);
          vbf[f] = *reinterpret_cast<const short8*>(Vb + off);
        }
        __builtin_amdgcn_s_setprio(1);
#pragma unroll
        for (int f = 0; f < 4; f++) {
          o_acc[0][f] = __builtin_amdgcn_mfma_f32_16x16x32_bf16(pa[0], vbf[f], o_acc[0][f], 0, 0, 0);
          o_acc[1][f] = __builtin_amdgcn_mfma_f32_16x16x32_bf16(pa[1], vbf[f], o_acc[1][f], 0, 0, 0);
        }
        acc_l[0] = __builtin_amdgcn_mfma_f32_16x16x32_bf16(pa[0], ones8, acc_l[0], 0, 0, 0);
        acc_l[1] = __builtin_amdgcn_mfma_f32_16x16x32_bf16(pa[1], ones8, acc_l[1], 0, 0, 0);
        __builtin_amdgcn_s_setprio(0);
      }
    }
    __syncthreads();
  }

#pragma unroll
  for (int m = 0; m < 2; m++) {
    float lr[4];
#pragma unroll
    for (int r = 0; r < 4; r++) lr[r] = 1.0f / acc_l[m][r];
#pragma unroll
    for (int f = 0; f < 4; f++)
#pragma unroll
      for (int r = 0; r < 4; r++) {
        int q = q0w + m * 16 + l4 * 4 + r;
        yb[(size_t)q * 1024 + f * 16 + l15] = f2bf(o_acc[m][f][r] * lr[r]);
      }
  }
}

// ---------------------------------------------------------------- launch
extern "C" void kernel_launch(void* const* d_in, const int* in_sizes, int n_in,
                              void* d_out, int out_size, void* d_ws, size_t ws_size,
                              hipStream_t stream) {
  const float* x = (const float*)d_in[0];
  const float* w_qkv = (const float*)d_in[1];
  const float* b_qkv = (const float*)d_in[2];
  const float* w_proj = (const float*)d_in[3];
  const float* b_proj = (const float*)d_in[4];
  float* out = (float*)d_out;
  char* ws = (char*)d_ws;

  const int M = 4 * 2048;
  unsigned short* x_bf = (unsigned short*)ws;                        // 16 MB
  unsigned short* wqkv_bf = (unsigned short*)(ws + (22ull << 20));   // 6 MB
  unsigned short* wproj_bf = (unsigned short*)(ws + (28ull << 20));  // 2 MB
  unsigned short* qk_buf = (unsigned short*)(ws + (30ull << 20));    // 32 MB [8192][2048]
  unsigned short* vt = (unsigned short*)(ws + (62ull << 20));        // 16 MB [4096][2048]
  unsigned short* y_bf = x_bf;  // reuse x region after QKV GEMM

  f32_to_bf16_kn<<<2048, 256, 0, stream>>>(x, x_bf, M * 1024);
  f32_to_bf16_kn<<<1024, 256, 0, stream>>>(w_qkv, wqkv_bf, 3072 * 1024);
  f32_to_bf16_kn<<<512, 256, 0, stream>>>(w_proj, wproj_bf, 1024 * 1024);

  // QKV: 256x192 tiles -> 16 x 32 = 512 blocks (exactly 2 waves of 256 CUs)
  gemm256_qkv_kn<<<dim3(16, 32), 512, 0, stream>>>(
      x_bf, wqkv_bf, b_qkv, qk_buf, vt, M, 3072, 1024);

  attn_kn<<<dim3(64, 16), 256, 0, stream>>>(qk_buf, vt, y_bf);

  // proj: 256x128 tiles -> 8 x 32 = 256 blocks (1/CU)
  gemm256_proj_kn<<<dim3(8, 32), 512, 0, stream>>>(
      y_bf, wproj_bf, b_proj, out, M, 1024, 1024);
}